// Round 1
// baseline (1003.469 us; speedup 1.0000x reference)
//
#include <hip/hip_runtime.h>

constexpr int E_EDGES = 500000;
constexpr int N_NODES = 20000;
constexpr int H       = 8;
constexpr int ROW     = 256;      // H*S = H*C*D floats per edge/node row (1024 B)
constexpr int CAP     = 128;      // per-node edge-list capacity (mean deg 25, ~26 sigma margin)
constexpr float SCALE = 0.0625f;  // 1/sqrt(H*S) = 1/16

// ---- workspace layout (32-bit words) ----
constexpr int OFF_DEN   = 0;                        // N*H floats (softmax denominators)
constexpr int OFF_COUNT = OFF_DEN + N_NODES * H;    // N ints (per-node degree)
constexpr int OFF_POS   = OFF_COUNT + N_NODES;      // N*CAP ints (per-node edge lists)
constexpr int OFF_EX    = OFF_POS + N_NODES * CAP;  // E*H floats (exp of logits)
constexpr int ZERO_WORDS = OFF_POS;                 // den + count must start at 0

__global__ __launch_bounds__(256) void zero_ws(int* __restrict__ ws) {
    int i = blockIdx.x * 256 + threadIdx.x;
    if (i < ZERO_WORDS) ws[i] = 0;
}

// One wave per edge. Lanes cooperatively float4-load the edge's k row (1 KB,
// coalesced) and the gathered q row at dst (1 KB contiguous). 8-lane groups
// reduce the per-head dot product. exp stored to ws; denominator atomically
// accumulated; lane 0 appends the edge to its destination node's list.
__global__ __launch_bounds__(256) void edge_pass1(
    const float* __restrict__ k, const float* __restrict__ q,
    const int* __restrict__ dst,
    float* __restrict__ ex, float* __restrict__ den,
    int* __restrict__ count, int* __restrict__ pos)
{
    int wave = (blockIdx.x * 256 + threadIdx.x) >> 6;
    int lane = threadIdx.x & 63;
    if (wave >= E_EDGES) return;
    const int e = wave;
    const int d = dst[e];   // broadcast load (all lanes same addr)

    const float4 k4 = *(const float4*)(k + (size_t)e * ROW + lane * 4);
    const float4 q4 = *(const float4*)(q + (size_t)d * ROW + lane * 4);
    float p = k4.x * q4.x + k4.y * q4.y + k4.z * q4.z + k4.w * q4.w;
    // reduce within each 8-lane head group (lanes 8h..8h+7 cover head h)
    p += __shfl_xor(p, 1);
    p += __shfl_xor(p, 2);
    p += __shfl_xor(p, 4);

    if ((lane & 7) == 0) {
        int h = lane >> 3;
        float exv = __expf(p * SCALE);   // no max-subtract needed: |p*SCALE| < ~2
        ex[(size_t)e * H + h] = exv;
        atomicAdd(den + d * H + h, exv);
    }
    if (lane == 0) {
        int s = atomicAdd(count + d, 1);
        if (s < CAP) pos[d * CAP + s] = e;
    }
}

// One wave per node. Walks the node's edge list; lane i handles head i>>3,
// floats [4i,4i+4) of each edge's v row (1 KB coalesced per edge). Attention
// weight a = ex/den is read per-lane (8-lane broadcast within a head group).
// Coalesced 1 KB output store; zero-degree nodes write zeros.
__global__ __launch_bounds__(256) void node_gather(
    const float* __restrict__ v, const float* __restrict__ ex,
    const float* __restrict__ den, const int* __restrict__ count,
    const int* __restrict__ pos, float* __restrict__ out)
{
    int wave = (blockIdx.x * 256 + threadIdx.x) >> 6;
    int lane = threadIdx.x & 63;
    if (wave >= N_NODES) return;
    const int n = wave;
    const int h = lane >> 3;

    const float dn  = den[n * H + h];
    const float inv = 1.0f / fmaxf(dn, 1e-9f);
    const int deg   = min(count[n], CAP);
    const int base  = n * CAP;

    float4 acc = {0.f, 0.f, 0.f, 0.f};
    int eid_next = (deg > 0) ? pos[base] : 0;
    for (int j = 0; j < deg; ++j) {
        int eid = eid_next;
        if (j + 1 < deg) eid_next = pos[base + j + 1];  // prefetch: break dep chain
        float a = ex[(size_t)eid * H + h] * inv;
        float4 v4 = *(const float4*)(v + (size_t)eid * ROW + lane * 4);
        acc.x += a * v4.x;
        acc.y += a * v4.y;
        acc.z += a * v4.z;
        acc.w += a * v4.w;
    }
    *(float4*)(out + (size_t)n * ROW + lane * 4) = acc;
}

extern "C" void kernel_launch(void* const* d_in, const int* in_sizes, int n_in,
                              void* d_out, int out_size, void* d_ws, size_t ws_size,
                              hipStream_t stream) {
    const float* v   = (const float*)d_in[0];
    const float* k   = (const float*)d_in[1];
    const float* q   = (const float*)d_in[2];
    const int*   dst = (const int*)d_in[3];
    float* out = (float*)d_out;

    float* den   = (float*)d_ws + OFF_DEN;
    int*   count = (int*)d_ws   + OFF_COUNT;
    int*   pos   = (int*)d_ws   + OFF_POS;
    float* ex    = (float*)d_ws + OFF_EX;

    zero_ws<<<(ZERO_WORDS + 255) / 256, 256, 0, stream>>>((int*)d_ws);
    edge_pass1<<<(E_EDGES * 64) / 256, 256, 0, stream>>>(k, q, dst, ex, den, count, pos);
    node_gather<<<(N_NODES * 64) / 256, 256, 0, stream>>>(v, ex, den, count, pos, out);
}

// Round 2
// 986.720 us; speedup vs baseline: 1.0170x; 1.0170x over previous
//
#include <hip/hip_runtime.h>

constexpr int E_EDGES = 500000;
constexpr int N_NODES = 20000;
constexpr int H       = 8;
constexpr int ROW     = 256;      // H*S = H*C*D floats per edge/node row (1024 B)
constexpr int CAP     = 128;      // per-node edge-list capacity (mean deg 25, ~20 sigma margin)
constexpr float SCALE = 0.0625f;  // 1/sqrt(H*S) = 1/16

typedef float f4 __attribute__((ext_vector_type(4)));

// ---- workspace layout (32-bit words) ----
constexpr int OFF_DEN   = 0;                        // N*H floats (softmax denominators)
constexpr int OFF_COUNT = OFF_DEN + N_NODES * H;    // N ints (per-node degree)
constexpr int OFF_POS   = OFF_COUNT + N_NODES;      // N*CAP ints (per-node edge lists)
constexpr int OFF_EX    = OFF_POS + N_NODES * CAP;  // E*H floats (exp of logits)
constexpr int ZERO_WORDS = OFF_POS;                 // den + count must start at 0

__global__ __launch_bounds__(256) void zero_ws(int* __restrict__ ws) {
    int i = blockIdx.x * 256 + threadIdx.x;
    if (i < ZERO_WORDS) ws[i] = 0;
}

// One wave per edge. Lanes cooperatively load the edge's k row (1 KB coalesced,
// nontemporal: k is single-use, keep it out of L2/L3 so q stays cached) and the
// gathered q row at dst (1 KB contiguous, cache-friendly: q is 20 MB, hot).
// 8-lane groups reduce the per-head dot product; exp stored; denominator
// atomically accumulated; lane 0 appends the edge to its dst node's list.
__global__ __launch_bounds__(256) void edge_pass1(
    const float* __restrict__ k, const float* __restrict__ q,
    const int* __restrict__ dst,
    float* __restrict__ ex, float* __restrict__ den,
    int* __restrict__ count, int* __restrict__ pos)
{
    int wave = (blockIdx.x * 256 + threadIdx.x) >> 6;
    int lane = threadIdx.x & 63;
    if (wave >= E_EDGES) return;
    const int e = wave;
    const int d = dst[e];   // broadcast load (all lanes same addr)

    const f4 k4 = __builtin_nontemporal_load((const f4*)(k + (size_t)e * ROW + lane * 4));
    const f4 q4 = *(const f4*)(q + (size_t)d * ROW + lane * 4);
    float p = k4.x * q4.x + k4.y * q4.y + k4.z * q4.z + k4.w * q4.w;
    // reduce within each 8-lane head group (lanes 8h..8h+7 cover head h)
    p += __shfl_xor(p, 1);
    p += __shfl_xor(p, 2);
    p += __shfl_xor(p, 4);

    if ((lane & 7) == 0) {
        int h = lane >> 3;
        float exv = __expf(p * SCALE);   // no max-subtract needed: |p*SCALE| small
        ex[(size_t)e * H + h] = exv;
        atomicAdd(den + d * H + h, exv);
    }
    if (lane == 0) {
        int s = atomicAdd(count + d, 1);
        if (s < CAP) pos[d * CAP + s] = e;
    }
}

// One wave per node. The wave loads its ENTIRE edge list up front (2 coalesced
// loads cover CAP=128) and broadcasts ids with __shfl — no load-chain gating
// the v addresses, so v loads pipeline to the BW limit. v is single-use →
// nontemporal. Accumulate unnormalized (out = sum ex*v), scale by 1/den once.
__global__ __launch_bounds__(256) void node_gather(
    const float* __restrict__ v, const float* __restrict__ ex,
    const float* __restrict__ den, const int* __restrict__ count,
    const int* __restrict__ pos, float* __restrict__ out)
{
    int wave = (blockIdx.x * 256 + threadIdx.x) >> 6;
    int lane = threadIdx.x & 63;
    if (wave >= N_NODES) return;
    const int n = wave;
    const int h = lane >> 3;

    const int deg  = min(count[n], CAP);
    const int base = n * CAP;

    // whole edge list into registers: lane L holds ids base+L and base+64+L
    int e_lo = (lane      < deg) ? pos[base + lane]      : 0;
    int e_hi = (lane + 64 < deg) ? pos[base + 64 + lane] : 0;

    f4 acc = {0.f, 0.f, 0.f, 0.f};
    for (int j = 0; j < deg; ++j) {
        int eid = __shfl(j < 64 ? e_lo : e_hi, j & 63);   // uniform select + broadcast
        float exv = ex[(size_t)eid * H + h];               // L2/L3-hot, 32 B per edge
        f4 v4 = __builtin_nontemporal_load((const f4*)(v + (size_t)eid * ROW + lane * 4));
        acc.x += exv * v4.x;
        acc.y += exv * v4.y;
        acc.z += exv * v4.z;
        acc.w += exv * v4.w;
    }

    const float dn  = den[n * H + h];
    const float inv = 1.0f / fmaxf(dn, 1e-9f);
    acc.x *= inv; acc.y *= inv; acc.z *= inv; acc.w *= inv;
    *(f4*)(out + (size_t)n * ROW + lane * 4) = acc;
}

extern "C" void kernel_launch(void* const* d_in, const int* in_sizes, int n_in,
                              void* d_out, int out_size, void* d_ws, size_t ws_size,
                              hipStream_t stream) {
    const float* v   = (const float*)d_in[0];
    const float* k   = (const float*)d_in[1];
    const float* q   = (const float*)d_in[2];
    const int*   dst = (const int*)d_in[3];
    float* out = (float*)d_out;

    float* den   = (float*)d_ws + OFF_DEN;
    int*   count = (int*)d_ws   + OFF_COUNT;
    int*   pos   = (int*)d_ws   + OFF_POS;
    float* ex    = (float*)d_ws + OFF_EX;

    zero_ws<<<(ZERO_WORDS + 255) / 256, 256, 0, stream>>>((int*)d_ws);
    edge_pass1<<<(E_EDGES * 64) / 256, 256, 0, stream>>>(k, q, dst, ex, den, count, pos);
    node_gather<<<(N_NODES * 64) / 256, 256, 0, stream>>>(v, ex, den, count, pos, out);
}